// Round 1
// baseline (5866.215 us; speedup 1.0000x reference)
//
#include <hip/hip_runtime.h>
#include <math.h>

// Problem constants (fixed by setup_inputs)
#define Bn   4
#define Nn   16384
#define CINn 32
#define DIMn 256
#define Sn   2048
#define KNEI 16
#define BNEPS 1e-5f
#define MROWS (Bn * Nn)   // 65536
#define SROWS (Bn * Sn)   // 8192

// ---------------------------------------------------------------------------
// K1: furthest point sampling. One workgroup (1024 threads) per batch.
// Each thread owns 16 contiguous points in registers. Per iteration:
// owner relays centroid via LDS, all threads update running min-dist,
// block argmax via sortable u64 key (dist_bits<<32 | ~idx) -> tie = min idx,
// exactly matching jnp.argmax first-occurrence semantics.
// fp contract OFF so d = ((dx*dx+dy*dy)+dz*dz) matches numpy bit-exactly.
// ---------------------------------------------------------------------------
__global__ __launch_bounds__(1024) void fps_kernel(const float* __restrict__ xyz,
                                                   int* __restrict__ fidx,
                                                   float* __restrict__ newxyz)
{
#pragma clang fp contract(off)
    __shared__ float s_cx, s_cy, s_cz;
    __shared__ int s_cur;
    __shared__ unsigned long long s_wkey[16];
    const int b = blockIdx.x;
    const int t = threadIdx.x;
    const float* px = xyz + (size_t)b * Nn * 3;
    float x[16], y[16], z[16], dist[16];
#pragma unroll
    for (int j = 0; j < 16; ++j) {
        const int n = t * 16 + j;
        x[j] = px[n * 3 + 0];
        y[j] = px[n * 3 + 1];
        z[j] = px[n * 3 + 2];
        dist[j] = __builtin_huge_valf();
    }
    if (t == 0) s_cur = 0;
    __syncthreads();
    for (int i = 0; i < Sn; ++i) {
        const int cur = s_cur;
        if (t == (cur >> 4)) {
            const int j = cur & 15;
            s_cx = x[j]; s_cy = y[j]; s_cz = z[j];
        }
        __syncthreads();
        if (t == 0) {
            fidx[b * Sn + i] = cur;
            newxyz[(size_t)(b * Sn + i) * 3 + 0] = s_cx;
            newxyz[(size_t)(b * Sn + i) * 3 + 1] = s_cy;
            newxyz[(size_t)(b * Sn + i) * 3 + 2] = s_cz;
        }
        if (i == Sn - 1) break;
        const float cx = s_cx, cy = s_cy, cz = s_cz;
        float bd = -1.0f;
        int bj = 0;
#pragma unroll
        for (int j = 0; j < 16; ++j) {
            const float dx = x[j] - cx;
            const float dy = y[j] - cy;
            const float dz = z[j] - cz;
            const float d = (dx * dx + dy * dy) + dz * dz;  // no fma (matches np)
            const float nd = fminf(dist[j], d);
            dist[j] = nd;
            if (nd > bd) { bd = nd; bj = j; }               // first-max kept
        }
        // sortable key: dist ascending in high bits (dist>=0), ~idx so tie -> min idx
        unsigned long long key =
            ((unsigned long long)__float_as_uint(bd) << 32) |
            (unsigned long long)(0xFFFFFFFFu - (unsigned)(t * 16 + bj));
#pragma unroll
        for (int off = 32; off > 0; off >>= 1) {
            const unsigned long long o = __shfl_xor(key, off);
            key = (o > key) ? o : key;
        }
        if ((t & 63) == 0) s_wkey[t >> 6] = key;
        __syncthreads();
        if (t < 16) {
            unsigned long long k2 = s_wkey[t];
#pragma unroll
            for (int off = 8; off > 0; off >>= 1) {
                const unsigned long long o = __shfl_xor(k2, off);
                k2 = (o > k2) ? o : k2;
            }
            if (t == 0) s_cur = (int)(0xFFFFFFFFu - (unsigned)(k2 & 0xFFFFFFFFull));
        }
        __syncthreads();
    }
}

// ---------------------------------------------------------------------------
// Generic f32 GEMM: C[r,c] = sum_k Ain[r,k] * B^[k,c] + bias[c], N = 256 fixed.
// BT:  B^[k,c] = Bm[c*K + k] (conv_w.T), else Bm[k*256 + c] (fc1_w).
// AFF: A element transformed relu(a*asc[k] + ash[k])  (BN1+relu fused into load).
// 64x64 tile, 256 threads, 4x4 microtile, KC=16.
// ---------------------------------------------------------------------------
template <bool BT, bool AFF>
__global__ __launch_bounds__(256) void gemm_k(const float* __restrict__ A,
                                              const float* __restrict__ Bm,
                                              const float* __restrict__ bias,
                                              const float* __restrict__ asc,
                                              const float* __restrict__ ash,
                                              float* __restrict__ C, int K)
{
    __shared__ float As[16][64];
    __shared__ float Bs[16][64];
    const int t = threadIdx.x;
    const int tx = t & 15;
    const int ty = t >> 4;
    const int r0 = blockIdx.x * 64;
    const int c0 = blockIdx.y * 64;
    const int rrA = t >> 2;          // 0..63
    const int kkA = (t & 3) * 4;     // 0,4,8,12
    float acc[4][4] = {};
    for (int kc = 0; kc < K; kc += 16) {
        {   // stage A tile (transposed into [k][r])
            const float4 v = *reinterpret_cast<const float4*>(
                &A[(size_t)(r0 + rrA) * K + kc + kkA]);
            float vv[4] = {v.x, v.y, v.z, v.w};
#pragma unroll
            for (int m = 0; m < 4; ++m) {
                float xv = vv[m];
                if (AFF) {
                    const int k = kc + kkA + m;
                    xv = fmaxf(fmaf(xv, asc[k], ash[k]), 0.0f);
                }
                As[kkA + m][rrA] = xv;
            }
        }
        if (BT) {
            const float4 v = *reinterpret_cast<const float4*>(
                &Bm[(size_t)(c0 + rrA) * K + kc + kkA]);
            Bs[kkA + 0][rrA] = v.x;
            Bs[kkA + 1][rrA] = v.y;
            Bs[kkA + 2][rrA] = v.z;
            Bs[kkA + 3][rrA] = v.w;
        } else {
            const int kk = t >> 4;
            const int cc = (t & 15) * 4;
            const float4 v = *reinterpret_cast<const float4*>(
                &Bm[(size_t)(kc + kk) * DIMn + c0 + cc]);
            *reinterpret_cast<float4*>(&Bs[kk][cc]) = v;
        }
        __syncthreads();
#pragma unroll
        for (int kk = 0; kk < 16; ++kk) {
            const float4 a = *reinterpret_cast<const float4*>(&As[kk][ty * 4]);
            const float4 bv = *reinterpret_cast<const float4*>(&Bs[kk][tx * 4]);
            const float av[4] = {a.x, a.y, a.z, a.w};
            const float bw[4] = {bv.x, bv.y, bv.z, bv.w};
#pragma unroll
            for (int i = 0; i < 4; ++i)
#pragma unroll
                for (int j = 0; j < 4; ++j)
                    acc[i][j] = fmaf(av[i], bw[j], acc[i][j]);
        }
        __syncthreads();
    }
    const int c = c0 + tx * 4;
#pragma unroll
    for (int i = 0; i < 4; ++i) {
        float4 o;
        o.x = acc[i][0] + bias[c + 0];
        o.y = acc[i][1] + bias[c + 1];
        o.z = acc[i][2] + bias[c + 2];
        o.w = acc[i][3] + bias[c + 3];
        *reinterpret_cast<float4*>(&C[(size_t)(r0 + ty * 4 + i) * DIMn + c]) = o;
    }
}

// ---------------------------------------------------------------------------
// points_ori gather: pre[bs,:] = h0[fidx[bs],:]  (must run before h0 is
// overwritten by the residual update).
// ---------------------------------------------------------------------------
__global__ __launch_bounds__(256) void gather_po_kernel(const float* __restrict__ h0,
                                                        const int* __restrict__ fidx,
                                                        float* __restrict__ pre)
{
    const int bs = blockIdx.x;
    const int b = bs >> 11;
    const int fid = fidx[bs];
    pre[(size_t)bs * DIMn + threadIdx.x] =
        h0[((size_t)b * Nn + fid) * DIMn + threadIdx.x];
}

// ---------------------------------------------------------------------------
// per-channel partial sums (sum, sumsq) for BatchNorm stats; fixed order,
// no atomics -> deterministic.
// ---------------------------------------------------------------------------
__global__ __launch_bounds__(256) void stats_partial(const float* __restrict__ X,
                                                     int rowsPerBlk,
                                                     float* __restrict__ ps,
                                                     float* __restrict__ pq)
{
    const int c = threadIdx.x;
    const size_t r0 = (size_t)blockIdx.x * rowsPerBlk;
    float s = 0.0f, q = 0.0f;
    for (int r = 0; r < rowsPerBlk; ++r) {
        const float v = X[(r0 + r) * DIMn + c];
        s += v;
        q = fmaf(v, v, q);
    }
    ps[blockIdx.x * DIMn + c] = s;
    pq[blockIdx.x * DIMn + c] = q;
}

__global__ __launch_bounds__(256) void bn_finalize(const float* __restrict__ ps,
                                                   const float* __restrict__ pq,
                                                   int nblk, float invN,
                                                   const float* __restrict__ g,
                                                   const float* __restrict__ bb,
                                                   float* __restrict__ sc,
                                                   float* __restrict__ sh)
{
    const int c = threadIdx.x;
    float s = 0.0f, q = 0.0f;
    for (int i = 0; i < nblk; ++i) {
        s += ps[i * DIMn + c];
        q += pq[i * DIMn + c];
    }
    const float mean = s * invN;
    const float var = q * invN - mean * mean;   // biased var
    const float r = 1.0f / sqrtf(var + BNEPS);
    const float scale = g[c] * r;
    sc[c] = scale;
    sh[c] = bb[c] - mean * scale;
}

// ---------------------------------------------------------------------------
// h = h + relu(A2*sc + sh), in place on h0. float4 vectorized.
// ---------------------------------------------------------------------------
__global__ __launch_bounds__(256) void residual_kernel(float* __restrict__ h,
                                                       const float* __restrict__ a2,
                                                       const float* __restrict__ sc,
                                                       const float* __restrict__ sh)
{
    const size_t i = (size_t)blockIdx.x * 256 + threadIdx.x;
    const int c4 = (int)(i & 63);
    float4 hv = reinterpret_cast<float4*>(h)[i];
    const float4 av = reinterpret_cast<const float4*>(a2)[i];
    const float4 s4 = reinterpret_cast<const float4*>(sc)[c4];
    const float4 b4 = reinterpret_cast<const float4*>(sh)[c4];
    hv.x += fmaxf(fmaf(av.x, s4.x, b4.x), 0.0f);
    hv.y += fmaxf(fmaf(av.y, s4.y, b4.y), 0.0f);
    hv.z += fmaxf(fmaf(av.z, s4.z, b4.z), 0.0f);
    hv.w += fmaxf(fmaf(av.w, s4.w, b4.w), 0.0f);
    reinterpret_cast<float4*>(h)[i] = hv;
}

// ---------------------------------------------------------------------------
// K7: per-query exact 16-NN + gather + channel maxpool + residual add.
// One block per (b,s). Distances use the reference formula
// (qq + bb) - 2*ab with fp contract OFF, stored as sortable u32 keys in LDS
// (64 KB). 16 rounds of block-argmin with cached per-thread minimum; only the
// extraction owner rescans its 64 slots. Tie-break: (d, idx) lexicographic ==
// stable top_k. Then pre[bs,:] += max_k h[nidx_k,:].
// ---------------------------------------------------------------------------
__global__ __launch_bounds__(256) void topk_group(const float* __restrict__ xyz,
                                                  const float* __restrict__ newxyz,
                                                  const float* __restrict__ h,
                                                  float* __restrict__ pre)
{
#pragma clang fp contract(off)
    __shared__ unsigned s_key[Nn];              // 64 KB (gfx950 allows >64KB/WG)
    __shared__ unsigned long long s_wred[4];
    __shared__ unsigned long long s_win;
    __shared__ int s_nidx[KNEI];
    const int bs = blockIdx.x;
    const int b = bs >> 11;
    const int t = threadIdx.x;
    const float* px = xyz + (size_t)b * Nn * 3;
    const float qx = newxyz[bs * 3 + 0];
    const float qy = newxyz[bs * 3 + 1];
    const float qz = newxyz[bs * 3 + 2];
    const float qq = (qx * qx + qy * qy) + qz * qz;
    unsigned long long mkey = ~0ull;
#pragma unroll 4
    for (int u = 0; u < 64; ++u) {
        const int n = t + (u << 8);
        const float bx = px[n * 3 + 0];
        const float by = px[n * 3 + 1];
        const float bz = px[n * 3 + 2];
        const float bb2 = (bx * bx + by * by) + bz * bz;
        const float ab = (qx * bx + qy * by) + qz * bz;
        const float d = (qq + bb2) - 2.0f * ab;   // exact reference formula
        unsigned u32 = __float_as_uint(d);
        u32 = ((int)u32 < 0) ? ~u32 : (u32 | 0x80000000u);  // sortable transform
        s_key[n] = u32;
        const unsigned long long k = ((unsigned long long)u32 << 32) | (unsigned)n;
        mkey = (k < mkey) ? k : mkey;
    }
    __syncthreads();
    for (int r = 0; r < KNEI; ++r) {
        unsigned long long k = mkey;
#pragma unroll
        for (int off = 32; off > 0; off >>= 1) {
            const unsigned long long o = __shfl_xor(k, off);
            k = (o < k) ? o : k;
        }
        if ((t & 63) == 0) s_wred[t >> 6] = k;
        __syncthreads();
        if (t == 0) {
            unsigned long long w = s_wred[0];
            if (s_wred[1] < w) w = s_wred[1];
            if (s_wred[2] < w) w = s_wred[2];
            if (s_wred[3] < w) w = s_wred[3];
            s_win = w;
            s_nidx[r] = (int)(unsigned)(w & 0xFFFFFFFFull);
        }
        __syncthreads();
        const unsigned long long w = s_win;
        if (w == mkey) {  // unique owner: invalidate + rescan own 64 slots
            const int wn = (int)(unsigned)(w & 0xFFFFFFFFull);
            s_key[wn] = 0xFFFFFFFFu;
            mkey = ~0ull;
#pragma unroll 4
            for (int u = 0; u < 64; ++u) {
                const int n = t + (u << 8);
                const unsigned long long kk =
                    ((unsigned long long)s_key[n] << 32) | (unsigned)n;
                mkey = (kk < mkey) ? kk : mkey;
            }
        }
        __syncthreads();
    }
    // gather + maxpool + add points_ori (already in pre)
    const float po = pre[(size_t)bs * DIMn + t];
    float m = -__builtin_huge_valf();
#pragma unroll
    for (int r = 0; r < KNEI; ++r) {
        const int n = s_nidx[r];
        m = fmaxf(m, h[((size_t)b * Nn + n) * DIMn + t]);
    }
    pre[(size_t)bs * DIMn + t] = po + m;
}

// ---------------------------------------------------------------------------
// final BN apply: out = pre*sc + sh
// ---------------------------------------------------------------------------
__global__ __launch_bounds__(256) void apply_bn_kernel(const float* __restrict__ pre,
                                                       const float* __restrict__ sc,
                                                       const float* __restrict__ sh,
                                                       float* __restrict__ out)
{
    const size_t i = (size_t)blockIdx.x * 256 + threadIdx.x;
    const int c4 = (int)(i & 63);
    const float4 v = reinterpret_cast<const float4*>(pre)[i];
    const float4 s4 = reinterpret_cast<const float4*>(sc)[c4];
    const float4 b4 = reinterpret_cast<const float4*>(sh)[c4];
    float4 o;
    o.x = fmaf(v.x, s4.x, b4.x);
    o.y = fmaf(v.y, s4.y, b4.y);
    o.z = fmaf(v.z, s4.z, b4.z);
    o.w = fmaf(v.w, s4.w, b4.w);
    reinterpret_cast<float4*>(out)[i] = o;
}

// ---------------------------------------------------------------------------
// Launch. Workspace layout (bytes), requires ws_size >= ~211 MB:
//   [0,64Mi)      h0  (fc1 out, then final h after residual)
//   [64Mi,128Mi)  A1  (conv1 pre-BN)
//   [128Mi,192Mi) A2  (conv2 pre-BN)
//   [192Mi,200Mi) pre (points_ori, then new_points pre-BN)  8 MB
//   [200Mi,+32K)  fps_idx
//   [201Mi, ...)  ps/pq partials (512 KB) + 6x256 scale/shift
// ---------------------------------------------------------------------------
extern "C" void kernel_launch(void* const* d_in, const int* in_sizes, int n_in,
                              void* d_out, int out_size, void* d_ws, size_t ws_size,
                              hipStream_t stream)
{
    (void)in_sizes; (void)n_in; (void)out_size; (void)ws_size;
    const float* xyz     = (const float*)d_in[0];
    const float* points  = (const float*)d_in[1];
    const float* fc1_w   = (const float*)d_in[2];
    const float* fc1_b   = (const float*)d_in[3];
    const float* conv1_w = (const float*)d_in[4];
    const float* conv1_b = (const float*)d_in[5];
    const float* conv2_w = (const float*)d_in[6];
    const float* conv2_b = (const float*)d_in[7];
    const float* bn1_g   = (const float*)d_in[8];
    const float* bn1_b   = (const float*)d_in[9];
    const float* bn2_g   = (const float*)d_in[10];
    const float* bn2_b   = (const float*)d_in[11];
    const float* bn_g    = (const float*)d_in[12];
    const float* bn_b    = (const float*)d_in[13];

    float* out = (float*)d_out;
    float* newxyz = out;                       // [4,2048,3]
    float* outpts = out + (size_t)Bn * Sn * 3; // [4,2048,256]

    char* w = (char*)d_ws;
    float* h0   = (float*)(w);
    float* A1   = (float*)(w + (64ull << 20));
    float* A2   = (float*)(w + (128ull << 20));
    float* pre  = (float*)(w + (192ull << 20));
    int*   fidx = (int*)  (w + (200ull << 20));
    float* ps   = (float*)(w + (201ull << 20));
    float* pq   = ps + 256 * 256;
    float* sc1  = pq + 256 * 256;
    float* sh1  = sc1 + 256;
    float* sc2  = sh1 + 256;
    float* sh2  = sc2 + 256;
    float* sc3  = sh2 + 256;
    float* sh3  = sc3 + 256;

    // 1. FPS (writes fps_idx + new_xyz directly into d_out)
    fps_kernel<<<Bn, 1024, 0, stream>>>(xyz, fidx, newxyz);
    // 2. h0 = points @ fc1_w + fc1_b
    gemm_k<false, false><<<dim3(MROWS / 64, DIMn / 64), 256, 0, stream>>>(
        points, fc1_w, fc1_b, nullptr, nullptr, h0, CINn);
    // 3. points_ori = h0[fps_idx]  (gathered BEFORE h0 is updated)
    gather_po_kernel<<<SROWS, 256, 0, stream>>>(h0, fidx, pre);
    // 4. A1 = h0 @ conv1_w.T + conv1_b ; BN1 stats
    gemm_k<true, false><<<dim3(MROWS / 64, DIMn / 64), 256, 0, stream>>>(
        h0, conv1_w, conv1_b, nullptr, nullptr, A1, DIMn);
    stats_partial<<<256, 256, 0, stream>>>(A1, MROWS / 256, ps, pq);
    bn_finalize<<<1, 256, 0, stream>>>(ps, pq, 256, 1.0f / MROWS, bn1_g, bn1_b, sc1, sh1);
    // 5. A2 = relu(BN1(A1)) @ conv2_w.T + conv2_b ; BN2 stats
    gemm_k<true, true><<<dim3(MROWS / 64, DIMn / 64), 256, 0, stream>>>(
        A1, conv2_w, conv2_b, sc1, sh1, A2, DIMn);
    stats_partial<<<256, 256, 0, stream>>>(A2, MROWS / 256, ps, pq);
    bn_finalize<<<1, 256, 0, stream>>>(ps, pq, 256, 1.0f / MROWS, bn2_g, bn2_b, sc2, sh2);
    // 6. h0 += relu(BN2(A2))   (h0 becomes final h)
    residual_kernel<<<(MROWS * DIMn / 4) / 256, 256, 0, stream>>>(h0, A2, sc2, sh2);
    // 7. 16-NN + gather + maxpool: pre = points_ori + max_k h[idx_k]
    topk_group<<<SROWS, 256, 0, stream>>>(xyz, newxyz, h0, pre);
    // 8. final BN over [B*S, D]
    stats_partial<<<64, 256, 0, stream>>>(pre, SROWS / 64, ps, pq);
    bn_finalize<<<1, 256, 0, stream>>>(ps, pq, 64, 1.0f / SROWS, bn_g, bn_b, sc3, sh3);
    apply_bn_kernel<<<(SROWS * DIMn / 4) / 256, 256, 0, stream>>>(pre, sc3, sh3, outpts);
}

// Round 2
// 5041.440 us; speedup vs baseline: 1.1636x; 1.1636x over previous
//
#include <hip/hip_runtime.h>
#include <math.h>

// Problem constants (fixed by setup_inputs)
#define Bn   4
#define Nn   16384
#define CINn 32
#define DIMn 256
#define Sn   2048
#define KNEI 16
#define BNEPS 1e-5f
#define MROWS (Bn * Nn)   // 65536
#define SROWS (Bn * Sn)   // 8192

// ---------------------------------------------------------------------------
// K1: furthest point sampling, v2 (register-resident).
// One workgroup (512 threads, 8 waves) per batch. Each thread owns 32 points
// (interleaved: n = j*512 + t) held ENTIRELY in VGPRs — launch_bounds(512,2)
// gives a 256-VGPR budget so the compiler cannot rematerialize the xyz loads
// (round-0 failure mode: FETCH_SIZE=440MB/dispatch from per-iteration L2
// re-reads under a 64-VGPR cap).
// Serial chain per iteration: uniform scalar-load of winner coords (s_load via
// readfirstlane) -> 32 dist updates -> wave butterfly argmax -> ONE barrier ->
// redundant per-wave 8-entry final reduce (double-buffered LDS, no 2nd
// barrier). Numerics identical to reference: contract OFF, d=(dx*dx+dy*dy)+dz*dz,
// running fminf, argmax tie -> lowest original index via key = dist<<32 | ~n.
// ---------------------------------------------------------------------------
__global__ __launch_bounds__(512, 2) void fps_kernel(const float* __restrict__ xyz,
                                                     int* __restrict__ fidx,
                                                     float* __restrict__ newxyz)
{
#pragma clang fp contract(off)
    __shared__ unsigned long long s_wkey[2][8];
    const int b = blockIdx.x;
    const int t = threadIdx.x;
    const int w = t >> 6;
    const int lane = t & 63;
    const float* __restrict__ px = xyz + (size_t)b * Nn * 3;
    float x[32], y[32], z[32], dist[32];
#pragma unroll
    for (int j = 0; j < 32; ++j) {
        const int n = j * 512 + t;
        x[j] = px[n * 3 + 0];
        y[j] = px[n * 3 + 1];
        z[j] = px[n * 3 + 2];
        dist[j] = __builtin_huge_valf();
    }
    int cur = 0;
    for (int i = 0; i < Sn; ++i) {
        const int wu = __builtin_amdgcn_readfirstlane(cur);
        // uniform index -> scalar loads (s_load), no owner-relay, no dynamic
        // register indexing
        const float cx = px[3 * wu + 0];
        const float cy = px[3 * wu + 1];
        const float cz = px[3 * wu + 2];
        if (t == 0) {
            fidx[b * Sn + i] = wu;
            newxyz[(size_t)(b * Sn + i) * 3 + 0] = cx;
            newxyz[(size_t)(b * Sn + i) * 3 + 1] = cy;
            newxyz[(size_t)(b * Sn + i) * 3 + 2] = cz;
        }
        if (i == Sn - 1) break;
        float bd = -1.0f;
#pragma unroll
        for (int j = 0; j < 32; ++j) {
            const float dx = x[j] - cx;
            const float dy = y[j] - cy;
            const float dz = z[j] - cz;
            const float d = (dx * dx + dy * dy) + dz * dz;  // no fma (matches np)
            const float nd = fminf(dist[j], d);
            dist[j] = nd;
            bd = fmaxf(bd, nd);
        }
        // recover arg: smallest j (= smallest n for this thread) matching bd
        unsigned bn = 0;
#pragma unroll
        for (int j = 31; j >= 0; --j)
            if (dist[j] == bd) bn = (unsigned)(j * 512 + t);
        // sortable key: larger dist wins; tie -> smaller n (via ~n)
        unsigned long long key =
            ((unsigned long long)__float_as_uint(bd) << 32) |
            (unsigned long long)(0xFFFFFFFFu - bn);
#pragma unroll
        for (int off = 32; off > 0; off >>= 1) {
            const unsigned long long o = __shfl_xor(key, off);
            key = (o > key) ? o : key;
        }
        if (lane == 0) s_wkey[i & 1][w] = key;
        __syncthreads();
        // every wave independently reduces the 8 per-wave keys (no 2nd barrier;
        // parity double-buffer makes the next iteration's writes race-free)
        unsigned long long k2 = (lane < 8) ? s_wkey[i & 1][lane] : 0ull;
#pragma unroll
        for (int off = 4; off > 0; off >>= 1) {
            const unsigned long long o = __shfl_xor(k2, off);
            k2 = (o > k2) ? o : k2;
        }
        k2 = __shfl(k2, 0);
        cur = (int)(0xFFFFFFFFu - (unsigned)(k2 & 0xFFFFFFFFull));
    }
}

// ---------------------------------------------------------------------------
// Generic f32 GEMM: C[r,c] = sum_k Ain[r,k] * B^[k,c] + bias[c], N = 256 fixed.
// BT:  B^[k,c] = Bm[c*K + k] (conv_w.T), else Bm[k*256 + c] (fc1_w).
// AFF: A element transformed relu(a*asc[k] + ash[k])  (BN1+relu fused into load).
// 64x64 tile, 256 threads, 4x4 microtile, KC=16.
// ---------------------------------------------------------------------------
template <bool BT, bool AFF>
__global__ __launch_bounds__(256) void gemm_k(const float* __restrict__ A,
                                              const float* __restrict__ Bm,
                                              const float* __restrict__ bias,
                                              const float* __restrict__ asc,
                                              const float* __restrict__ ash,
                                              float* __restrict__ C, int K)
{
    __shared__ float As[16][64];
    __shared__ float Bs[16][64];
    const int t = threadIdx.x;
    const int tx = t & 15;
    const int ty = t >> 4;
    const int r0 = blockIdx.x * 64;
    const int c0 = blockIdx.y * 64;
    const int rrA = t >> 2;          // 0..63
    const int kkA = (t & 3) * 4;     // 0,4,8,12
    float acc[4][4] = {};
    for (int kc = 0; kc < K; kc += 16) {
        {   // stage A tile (transposed into [k][r])
            const float4 v = *reinterpret_cast<const float4*>(
                &A[(size_t)(r0 + rrA) * K + kc + kkA]);
            float vv[4] = {v.x, v.y, v.z, v.w};
#pragma unroll
            for (int m = 0; m < 4; ++m) {
                float xv = vv[m];
                if (AFF) {
                    const int k = kc + kkA + m;
                    xv = fmaxf(fmaf(xv, asc[k], ash[k]), 0.0f);
                }
                As[kkA + m][rrA] = xv;
            }
        }
        if (BT) {
            const float4 v = *reinterpret_cast<const float4*>(
                &Bm[(size_t)(c0 + rrA) * K + kc + kkA]);
            Bs[kkA + 0][rrA] = v.x;
            Bs[kkA + 1][rrA] = v.y;
            Bs[kkA + 2][rrA] = v.z;
            Bs[kkA + 3][rrA] = v.w;
        } else {
            const int kk = t >> 4;
            const int cc = (t & 15) * 4;
            const float4 v = *reinterpret_cast<const float4*>(
                &Bm[(size_t)(kc + kk) * DIMn + c0 + cc]);
            *reinterpret_cast<float4*>(&Bs[kk][cc]) = v;
        }
        __syncthreads();
#pragma unroll
        for (int kk = 0; kk < 16; ++kk) {
            const float4 a = *reinterpret_cast<const float4*>(&As[kk][ty * 4]);
            const float4 bv = *reinterpret_cast<const float4*>(&Bs[kk][tx * 4]);
            const float av[4] = {a.x, a.y, a.z, a.w};
            const float bw[4] = {bv.x, bv.y, bv.z, bv.w};
#pragma unroll
            for (int i = 0; i < 4; ++i)
#pragma unroll
                for (int j = 0; j < 4; ++j)
                    acc[i][j] = fmaf(av[i], bw[j], acc[i][j]);
        }
        __syncthreads();
    }
    const int c = c0 + tx * 4;
#pragma unroll
    for (int i = 0; i < 4; ++i) {
        float4 o;
        o.x = acc[i][0] + bias[c + 0];
        o.y = acc[i][1] + bias[c + 1];
        o.z = acc[i][2] + bias[c + 2];
        o.w = acc[i][3] + bias[c + 3];
        *reinterpret_cast<float4*>(&C[(size_t)(r0 + ty * 4 + i) * DIMn + c]) = o;
    }
}

// ---------------------------------------------------------------------------
// points_ori gather: pre[bs,:] = h0[fidx[bs],:]  (must run before h0 is
// overwritten by the residual update).
// ---------------------------------------------------------------------------
__global__ __launch_bounds__(256) void gather_po_kernel(const float* __restrict__ h0,
                                                        const int* __restrict__ fidx,
                                                        float* __restrict__ pre)
{
    const int bs = blockIdx.x;
    const int b = bs >> 11;
    const int fid = fidx[bs];
    pre[(size_t)bs * DIMn + threadIdx.x] =
        h0[((size_t)b * Nn + fid) * DIMn + threadIdx.x];
}

// ---------------------------------------------------------------------------
// per-channel partial sums (sum, sumsq) for BatchNorm stats; fixed order,
// no atomics -> deterministic.
// ---------------------------------------------------------------------------
__global__ __launch_bounds__(256) void stats_partial(const float* __restrict__ X,
                                                     int rowsPerBlk,
                                                     float* __restrict__ ps,
                                                     float* __restrict__ pq)
{
    const int c = threadIdx.x;
    const size_t r0 = (size_t)blockIdx.x * rowsPerBlk;
    float s = 0.0f, q = 0.0f;
    for (int r = 0; r < rowsPerBlk; ++r) {
        const float v = X[(r0 + r) * DIMn + c];
        s += v;
        q = fmaf(v, v, q);
    }
    ps[blockIdx.x * DIMn + c] = s;
    pq[blockIdx.x * DIMn + c] = q;
}

__global__ __launch_bounds__(256) void bn_finalize(const float* __restrict__ ps,
                                                   const float* __restrict__ pq,
                                                   int nblk, float invN,
                                                   const float* __restrict__ g,
                                                   const float* __restrict__ bb,
                                                   float* __restrict__ sc,
                                                   float* __restrict__ sh)
{
    const int c = threadIdx.x;
    float s = 0.0f, q = 0.0f;
    for (int i = 0; i < nblk; ++i) {
        s += ps[i * DIMn + c];
        q += pq[i * DIMn + c];
    }
    const float mean = s * invN;
    const float var = q * invN - mean * mean;   // biased var
    const float r = 1.0f / sqrtf(var + BNEPS);
    const float scale = g[c] * r;
    sc[c] = scale;
    sh[c] = bb[c] - mean * scale;
}

// ---------------------------------------------------------------------------
// h = h + relu(A2*sc + sh), in place on h0. float4 vectorized.
// ---------------------------------------------------------------------------
__global__ __launch_bounds__(256) void residual_kernel(float* __restrict__ h,
                                                       const float* __restrict__ a2,
                                                       const float* __restrict__ sc,
                                                       const float* __restrict__ sh)
{
    const size_t i = (size_t)blockIdx.x * 256 + threadIdx.x;
    const int c4 = (int)(i & 63);
    float4 hv = reinterpret_cast<float4*>(h)[i];
    const float4 av = reinterpret_cast<const float4*>(a2)[i];
    const float4 s4 = reinterpret_cast<const float4*>(sc)[c4];
    const float4 b4 = reinterpret_cast<const float4*>(sh)[c4];
    hv.x += fmaxf(fmaf(av.x, s4.x, b4.x), 0.0f);
    hv.y += fmaxf(fmaf(av.y, s4.y, b4.y), 0.0f);
    hv.z += fmaxf(fmaf(av.z, s4.z, b4.z), 0.0f);
    hv.w += fmaxf(fmaf(av.w, s4.w, b4.w), 0.0f);
    reinterpret_cast<float4*>(h)[i] = hv;
}

// ---------------------------------------------------------------------------
// K7: per-query exact 16-NN + gather + channel maxpool + residual add.
// One block per (b,s). Distances use the reference formula
// (qq + bb) - 2*ab with fp contract OFF, stored as sortable u32 keys in LDS
// (64 KB). 16 rounds of block-argmin with cached per-thread minimum; only the
// extraction owner rescans its 64 slots. Tie-break: (d, idx) lexicographic ==
// stable top_k. Then pre[bs,:] += max_k h[nidx_k,:].
// ---------------------------------------------------------------------------
__global__ __launch_bounds__(256) void topk_group(const float* __restrict__ xyz,
                                                  const float* __restrict__ newxyz,
                                                  const float* __restrict__ h,
                                                  float* __restrict__ pre)
{
#pragma clang fp contract(off)
    __shared__ unsigned s_key[Nn];              // 64 KB
    __shared__ unsigned long long s_wred[4];
    __shared__ unsigned long long s_win;
    __shared__ int s_nidx[KNEI];
    const int bs = blockIdx.x;
    const int b = bs >> 11;
    const int t = threadIdx.x;
    const float* px = xyz + (size_t)b * Nn * 3;
    const float qx = newxyz[bs * 3 + 0];
    const float qy = newxyz[bs * 3 + 1];
    const float qz = newxyz[bs * 3 + 2];
    const float qq = (qx * qx + qy * qy) + qz * qz;
    unsigned long long mkey = ~0ull;
#pragma unroll 4
    for (int u = 0; u < 64; ++u) {
        const int n = t + (u << 8);
        const float bx = px[n * 3 + 0];
        const float by = px[n * 3 + 1];
        const float bz = px[n * 3 + 2];
        const float bb2 = (bx * bx + by * by) + bz * bz;
        const float ab = (qx * bx + qy * by) + qz * bz;
        const float d = (qq + bb2) - 2.0f * ab;   // exact reference formula
        unsigned u32 = __float_as_uint(d);
        u32 = ((int)u32 < 0) ? ~u32 : (u32 | 0x80000000u);  // sortable transform
        s_key[n] = u32;
        const unsigned long long k = ((unsigned long long)u32 << 32) | (unsigned)n;
        mkey = (k < mkey) ? k : mkey;
    }
    __syncthreads();
    for (int r = 0; r < KNEI; ++r) {
        unsigned long long k = mkey;
#pragma unroll
        for (int off = 32; off > 0; off >>= 1) {
            const unsigned long long o = __shfl_xor(k, off);
            k = (o < k) ? o : k;
        }
        if ((t & 63) == 0) s_wred[t >> 6] = k;
        __syncthreads();
        if (t == 0) {
            unsigned long long w = s_wred[0];
            if (s_wred[1] < w) w = s_wred[1];
            if (s_wred[2] < w) w = s_wred[2];
            if (s_wred[3] < w) w = s_wred[3];
            s_win = w;
            s_nidx[r] = (int)(unsigned)(w & 0xFFFFFFFFull);
        }
        __syncthreads();
        const unsigned long long w = s_win;
        if (w == mkey) {  // unique owner: invalidate + rescan own 64 slots
            const int wn = (int)(unsigned)(w & 0xFFFFFFFFull);
            s_key[wn] = 0xFFFFFFFFu;
            mkey = ~0ull;
#pragma unroll 4
            for (int u = 0; u < 64; ++u) {
                const int n = t + (u << 8);
                const unsigned long long kk =
                    ((unsigned long long)s_key[n] << 32) | (unsigned)n;
                mkey = (kk < mkey) ? kk : mkey;
            }
        }
        __syncthreads();
    }
    // gather + maxpool + add points_ori (already in pre)
    const float po = pre[(size_t)bs * DIMn + t];
    float m = -__builtin_huge_valf();
#pragma unroll
    for (int r = 0; r < KNEI; ++r) {
        const int n = s_nidx[r];
        m = fmaxf(m, h[((size_t)b * Nn + n) * DIMn + t]);
    }
    pre[(size_t)bs * DIMn + t] = po + m;
}

// ---------------------------------------------------------------------------
// final BN apply: out = pre*sc + sh
// ---------------------------------------------------------------------------
__global__ __launch_bounds__(256) void apply_bn_kernel(const float* __restrict__ pre,
                                                       const float* __restrict__ sc,
                                                       const float* __restrict__ sh,
                                                       float* __restrict__ out)
{
    const size_t i = (size_t)blockIdx.x * 256 + threadIdx.x;
    const int c4 = (int)(i & 63);
    const float4 v = reinterpret_cast<const float4*>(pre)[i];
    const float4 s4 = reinterpret_cast<const float4*>(sc)[c4];
    const float4 b4 = reinterpret_cast<const float4*>(sh)[c4];
    float4 o;
    o.x = fmaf(v.x, s4.x, b4.x);
    o.y = fmaf(v.y, s4.y, b4.y);
    o.z = fmaf(v.z, s4.z, b4.z);
    o.w = fmaf(v.w, s4.w, b4.w);
    reinterpret_cast<float4*>(out)[i] = o;
}

// ---------------------------------------------------------------------------
// Launch. Workspace layout (bytes), requires ws_size >= ~211 MB:
//   [0,64Mi)      h0  (fc1 out, then final h after residual)
//   [64Mi,128Mi)  A1  (conv1 pre-BN)
//   [128Mi,192Mi) A2  (conv2 pre-BN)
//   [192Mi,200Mi) pre (points_ori, then new_points pre-BN)  8 MB
//   [200Mi,+32K)  fps_idx
//   [201Mi, ...)  ps/pq partials (512 KB) + 6x256 scale/shift
// ---------------------------------------------------------------------------
extern "C" void kernel_launch(void* const* d_in, const int* in_sizes, int n_in,
                              void* d_out, int out_size, void* d_ws, size_t ws_size,
                              hipStream_t stream)
{
    (void)in_sizes; (void)n_in; (void)out_size; (void)ws_size;
    const float* xyz     = (const float*)d_in[0];
    const float* points  = (const float*)d_in[1];
    const float* fc1_w   = (const float*)d_in[2];
    const float* fc1_b   = (const float*)d_in[3];
    const float* conv1_w = (const float*)d_in[4];
    const float* conv1_b = (const float*)d_in[5];
    const float* conv2_w = (const float*)d_in[6];
    const float* conv2_b = (const float*)d_in[7];
    const float* bn1_g   = (const float*)d_in[8];
    const float* bn1_b   = (const float*)d_in[9];
    const float* bn2_g   = (const float*)d_in[10];
    const float* bn2_b   = (const float*)d_in[11];
    const float* bn_g    = (const float*)d_in[12];
    const float* bn_b    = (const float*)d_in[13];

    float* out = (float*)d_out;
    float* newxyz = out;                       // [4,2048,3]
    float* outpts = out + (size_t)Bn * Sn * 3; // [4,2048,256]

    char* w = (char*)d_ws;
    float* h0   = (float*)(w);
    float* A1   = (float*)(w + (64ull << 20));
    float* A2   = (float*)(w + (128ull << 20));
    float* pre  = (float*)(w + (192ull << 20));
    int*   fidx = (int*)  (w + (200ull << 20));
    float* ps   = (float*)(w + (201ull << 20));
    float* pq   = ps + 256 * 256;
    float* sc1  = pq + 256 * 256;
    float* sh1  = sc1 + 256;
    float* sc2  = sh1 + 256;
    float* sh2  = sc2 + 256;
    float* sc3  = sh2 + 256;
    float* sh3  = sc3 + 256;

    // 1. FPS (writes fps_idx + new_xyz directly into d_out)
    fps_kernel<<<Bn, 512, 0, stream>>>(xyz, fidx, newxyz);
    // 2. h0 = points @ fc1_w + fc1_b
    gemm_k<false, false><<<dim3(MROWS / 64, DIMn / 64), 256, 0, stream>>>(
        points, fc1_w, fc1_b, nullptr, nullptr, h0, CINn);
    // 3. points_ori = h0[fps_idx]  (gathered BEFORE h0 is updated)
    gather_po_kernel<<<SROWS, 256, 0, stream>>>(h0, fidx, pre);
    // 4. A1 = h0 @ conv1_w.T + conv1_b ; BN1 stats
    gemm_k<true, false><<<dim3(MROWS / 64, DIMn / 64), 256, 0, stream>>>(
        h0, conv1_w, conv1_b, nullptr, nullptr, A1, DIMn);
    stats_partial<<<256, 256, 0, stream>>>(A1, MROWS / 256, ps, pq);
    bn_finalize<<<1, 256, 0, stream>>>(ps, pq, 256, 1.0f / MROWS, bn1_g, bn1_b, sc1, sh1);
    // 5. A2 = relu(BN1(A1)) @ conv2_w.T + conv2_b ; BN2 stats
    gemm_k<true, true><<<dim3(MROWS / 64, DIMn / 64), 256, 0, stream>>>(
        A1, conv2_w, conv2_b, sc1, sh1, A2, DIMn);
    stats_partial<<<256, 256, 0, stream>>>(A2, MROWS / 256, ps, pq);
    bn_finalize<<<1, 256, 0, stream>>>(ps, pq, 256, 1.0f / MROWS, bn2_g, bn2_b, sc2, sh2);
    // 6. h0 += relu(BN2(A2))   (h0 becomes final h)
    residual_kernel<<<(MROWS * DIMn / 4) / 256, 256, 0, stream>>>(h0, A2, sc2, sh2);
    // 7. 16-NN + gather + maxpool: pre = points_ori + max_k h[idx_k]
    topk_group<<<SROWS, 256, 0, stream>>>(xyz, newxyz, h0, pre);
    // 8. final BN over [B*S, D]
    stats_partial<<<64, 256, 0, stream>>>(pre, SROWS / 64, ps, pq);
    bn_finalize<<<1, 256, 0, stream>>>(ps, pq, 64, 1.0f / SROWS, bn_g, bn_b, sc3, sh3);
    apply_bn_kernel<<<(SROWS * DIMn / 4) / 256, 256, 0, stream>>>(pre, sc3, sh3, outpts);
}

// Round 3
// 4913.853 us; speedup vs baseline: 1.1938x; 1.0260x over previous
//
#include <hip/hip_runtime.h>
#include <math.h>

// Problem constants (fixed by setup_inputs)
#define Bn   4
#define Nn   16384
#define CINn 32
#define DIMn 256
#define Sn   2048
#define KNEI 16
#define BNEPS 1e-5f
#define MROWS (Bn * Nn)   // 65536
#define SROWS (Bn * Sn)   // 8192

// ---------------------------------------------------------------------------
// K1: furthest point sampling, v3 (register-resident, asm-pinned).
// Round-2 lesson: even with a 256-VGPR budget the compiler rematerializes
// read-only global loads (VGPR_Count=84, FETCH_SIZE=405MB/dispatch = full
// xyz re-read x2048). Fix: asm volatile "+v" pins on x/y/z after the init
// load -- the values become opaque, remat impossible, so all 96+32 floats
// stay in VGPRs and the loop is pure VALU.
// Numerics identical to reference: contract OFF, d=(dx*dx+dy*dy)+dz*dz,
// running fminf, argmax tie -> lowest index via key = dist<<32 | ~n.
// ---------------------------------------------------------------------------
__global__ __launch_bounds__(512, 2) void fps_kernel(const float* __restrict__ xyz,
                                                     int* __restrict__ fidx,
                                                     float* __restrict__ newxyz)
{
#pragma clang fp contract(off)
    __shared__ unsigned long long s_wkey[2][8];
    const int b = blockIdx.x;
    const int t = threadIdx.x;
    const int w = t >> 6;
    const int lane = t & 63;
    const float* __restrict__ px = xyz + (size_t)b * Nn * 3;
    float x[32], y[32], z[32], dist[32];
#pragma unroll
    for (int j = 0; j < 32; ++j) {
        const int n = j * 512 + t;
        x[j] = px[n * 3 + 0];
        y[j] = px[n * 3 + 1];
        z[j] = px[n * 3 + 2];
        dist[j] = __builtin_huge_valf();
    }
    // pin: forbid rematerialization of the global loads (round-2 failure mode)
#pragma unroll
    for (int j = 0; j < 32; ++j) {
        asm volatile("" : "+v"(x[j]));
        asm volatile("" : "+v"(y[j]));
        asm volatile("" : "+v"(z[j]));
    }
    int cur = 0;
    for (int i = 0; i < Sn; ++i) {
        const int wu = __builtin_amdgcn_readfirstlane(cur);
        // uniform index -> scalar loads, no owner-relay, no dynamic reg indexing
        const float cx = px[3 * wu + 0];
        const float cy = px[3 * wu + 1];
        const float cz = px[3 * wu + 2];
        if (t == 0) {
            fidx[b * Sn + i] = wu;
            newxyz[(size_t)(b * Sn + i) * 3 + 0] = cx;
            newxyz[(size_t)(b * Sn + i) * 3 + 1] = cy;
            newxyz[(size_t)(b * Sn + i) * 3 + 2] = cz;
        }
        if (i == Sn - 1) break;
        float bd = -1.0f;
#pragma unroll
        for (int j = 0; j < 32; ++j) {
            const float dx = x[j] - cx;
            const float dy = y[j] - cy;
            const float dz = z[j] - cz;
            const float d = (dx * dx + dy * dy) + dz * dz;  // no fma (matches np)
            const float nd = fminf(dist[j], d);
            dist[j] = nd;
            bd = fmaxf(bd, nd);
        }
        // recover arg: smallest j (= smallest n for this thread) matching bd
        unsigned bn = 0;
#pragma unroll
        for (int j = 31; j >= 0; --j)
            if (dist[j] == bd) bn = (unsigned)(j * 512 + t);
        // sortable key: larger dist wins; tie -> smaller n (via ~n)
        unsigned long long key =
            ((unsigned long long)__float_as_uint(bd) << 32) |
            (unsigned long long)(0xFFFFFFFFu - bn);
#pragma unroll
        for (int off = 32; off > 0; off >>= 1) {
            const unsigned long long o = __shfl_xor(key, off);
            key = (o > key) ? o : key;
        }
        if (lane == 0) s_wkey[i & 1][w] = key;
        __syncthreads();
        // every wave independently reduces the 8 per-wave keys (no 2nd barrier;
        // parity double-buffer makes the next iteration's writes race-free)
        unsigned long long k2 = (lane < 8) ? s_wkey[i & 1][lane] : 0ull;
#pragma unroll
        for (int off = 4; off > 0; off >>= 1) {
            const unsigned long long o = __shfl_xor(k2, off);
            k2 = (o > k2) ? o : k2;
        }
        k2 = __shfl(k2, 0);
        cur = (int)(0xFFFFFFFFu - (unsigned)(k2 & 0xFFFFFFFFull));
    }
}

// ---------------------------------------------------------------------------
// Generic f32 GEMM: C[r,c] = sum_k Ain[r,k] * B^[k,c] + bias[c], N = 256 fixed.
// BT:  B^[k,c] = Bm[c*K + k] (conv_w.T), else Bm[k*256 + c] (fc1_w).
// AFF: A element transformed relu(a*asc[k] + ash[k])  (BN1+relu fused into load).
// 64x64 tile, 256 threads, 4x4 microtile, KC=16.
// ---------------------------------------------------------------------------
template <bool BT, bool AFF>
__global__ __launch_bounds__(256) void gemm_k(const float* __restrict__ A,
                                              const float* __restrict__ Bm,
                                              const float* __restrict__ bias,
                                              const float* __restrict__ asc,
                                              const float* __restrict__ ash,
                                              float* __restrict__ C, int K)
{
    __shared__ float As[16][64];
    __shared__ float Bs[16][64];
    const int t = threadIdx.x;
    const int tx = t & 15;
    const int ty = t >> 4;
    const int r0 = blockIdx.x * 64;
    const int c0 = blockIdx.y * 64;
    const int rrA = t >> 2;          // 0..63
    const int kkA = (t & 3) * 4;     // 0,4,8,12
    float acc[4][4] = {};
    for (int kc = 0; kc < K; kc += 16) {
        {   // stage A tile (transposed into [k][r])
            const float4 v = *reinterpret_cast<const float4*>(
                &A[(size_t)(r0 + rrA) * K + kc + kkA]);
            float vv[4] = {v.x, v.y, v.z, v.w};
#pragma unroll
            for (int m = 0; m < 4; ++m) {
                float xv = vv[m];
                if (AFF) {
                    const int k = kc + kkA + m;
                    xv = fmaxf(fmaf(xv, asc[k], ash[k]), 0.0f);
                }
                As[kkA + m][rrA] = xv;
            }
        }
        if (BT) {
            const float4 v = *reinterpret_cast<const float4*>(
                &Bm[(size_t)(c0 + rrA) * K + kc + kkA]);
            Bs[kkA + 0][rrA] = v.x;
            Bs[kkA + 1][rrA] = v.y;
            Bs[kkA + 2][rrA] = v.z;
            Bs[kkA + 3][rrA] = v.w;
        } else {
            const int kk = t >> 4;
            const int cc = (t & 15) * 4;
            const float4 v = *reinterpret_cast<const float4*>(
                &Bm[(size_t)(kc + kk) * DIMn + c0 + cc]);
            *reinterpret_cast<float4*>(&Bs[kk][cc]) = v;
        }
        __syncthreads();
#pragma unroll
        for (int kk = 0; kk < 16; ++kk) {
            const float4 a = *reinterpret_cast<const float4*>(&As[kk][ty * 4]);
            const float4 bv = *reinterpret_cast<const float4*>(&Bs[kk][tx * 4]);
            const float av[4] = {a.x, a.y, a.z, a.w};
            const float bw[4] = {bv.x, bv.y, bv.z, bv.w};
#pragma unroll
            for (int i = 0; i < 4; ++i)
#pragma unroll
                for (int j = 0; j < 4; ++j)
                    acc[i][j] = fmaf(av[i], bw[j], acc[i][j]);
        }
        __syncthreads();
    }
    const int c = c0 + tx * 4;
#pragma unroll
    for (int i = 0; i < 4; ++i) {
        float4 o;
        o.x = acc[i][0] + bias[c + 0];
        o.y = acc[i][1] + bias[c + 1];
        o.z = acc[i][2] + bias[c + 2];
        o.w = acc[i][3] + bias[c + 3];
        *reinterpret_cast<float4*>(&C[(size_t)(r0 + ty * 4 + i) * DIMn + c]) = o;
    }
}

// ---------------------------------------------------------------------------
// points_ori gather: pre[bs,:] = h0[fidx[bs],:]  (must run before h0 is
// overwritten by the residual update).
// ---------------------------------------------------------------------------
__global__ __launch_bounds__(256) void gather_po_kernel(const float* __restrict__ h0,
                                                        const int* __restrict__ fidx,
                                                        float* __restrict__ pre)
{
    const int bs = blockIdx.x;
    const int b = bs >> 11;
    const int fid = fidx[bs];
    pre[(size_t)bs * DIMn + threadIdx.x] =
        h0[((size_t)b * Nn + fid) * DIMn + threadIdx.x];
}

// ---------------------------------------------------------------------------
// per-channel partial sums (sum, sumsq) for BatchNorm stats; fixed order,
// no atomics -> deterministic.
// ---------------------------------------------------------------------------
__global__ __launch_bounds__(256) void stats_partial(const float* __restrict__ X,
                                                     int rowsPerBlk,
                                                     float* __restrict__ ps,
                                                     float* __restrict__ pq)
{
    const int c = threadIdx.x;
    const size_t r0 = (size_t)blockIdx.x * rowsPerBlk;
    float s = 0.0f, q = 0.0f;
    for (int r = 0; r < rowsPerBlk; ++r) {
        const float v = X[(r0 + r) * DIMn + c];
        s += v;
        q = fmaf(v, v, q);
    }
    ps[blockIdx.x * DIMn + c] = s;
    pq[blockIdx.x * DIMn + c] = q;
}

__global__ __launch_bounds__(256) void bn_finalize(const float* __restrict__ ps,
                                                   const float* __restrict__ pq,
                                                   int nblk, float invN,
                                                   const float* __restrict__ g,
                                                   const float* __restrict__ bb,
                                                   float* __restrict__ sc,
                                                   float* __restrict__ sh)
{
    const int c = threadIdx.x;
    float s = 0.0f, q = 0.0f;
    for (int i = 0; i < nblk; ++i) {
        s += ps[i * DIMn + c];
        q += pq[i * DIMn + c];
    }
    const float mean = s * invN;
    const float var = q * invN - mean * mean;   // biased var
    const float r = 1.0f / sqrtf(var + BNEPS);
    const float scale = g[c] * r;
    sc[c] = scale;
    sh[c] = bb[c] - mean * scale;
}

// ---------------------------------------------------------------------------
// h = h + relu(A2*sc + sh), in place on h0. float4 vectorized.
// ---------------------------------------------------------------------------
__global__ __launch_bounds__(256) void residual_kernel(float* __restrict__ h,
                                                       const float* __restrict__ a2,
                                                       const float* __restrict__ sc,
                                                       const float* __restrict__ sh)
{
    const size_t i = (size_t)blockIdx.x * 256 + threadIdx.x;
    const int c4 = (int)(i & 63);
    float4 hv = reinterpret_cast<float4*>(h)[i];
    const float4 av = reinterpret_cast<const float4*>(a2)[i];
    const float4 s4 = reinterpret_cast<const float4*>(sc)[c4];
    const float4 b4 = reinterpret_cast<const float4*>(sh)[c4];
    hv.x += fmaxf(fmaf(av.x, s4.x, b4.x), 0.0f);
    hv.y += fmaxf(fmaf(av.y, s4.y, b4.y), 0.0f);
    hv.z += fmaxf(fmaf(av.z, s4.z, b4.z), 0.0f);
    hv.w += fmaxf(fmaf(av.w, s4.w, b4.w), 0.0f);
    reinterpret_cast<float4*>(h)[i] = hv;
}

// ---------------------------------------------------------------------------
// K7: per-query exact 16-NN + gather + channel maxpool + residual add.
// One block per (b,s). Distances use the reference formula
// (qq + bb) - 2*ab with fp contract OFF, stored as sortable u32 keys in LDS
// (64 KB). 16 rounds of block-argmin with cached per-thread minimum; only the
// extraction owner rescans its 64 slots. Tie-break: (d, idx) lexicographic ==
// stable top_k. Then pre[bs,:] += max_k h[nidx_k,:].
// ---------------------------------------------------------------------------
__global__ __launch_bounds__(256) void topk_group(const float* __restrict__ xyz,
                                                  const float* __restrict__ newxyz,
                                                  const float* __restrict__ h,
                                                  float* __restrict__ pre)
{
#pragma clang fp contract(off)
    __shared__ unsigned s_key[Nn];              // 64 KB
    __shared__ unsigned long long s_wred[4];
    __shared__ unsigned long long s_win;
    __shared__ int s_nidx[KNEI];
    const int bs = blockIdx.x;
    const int b = bs >> 11;
    const int t = threadIdx.x;
    const float* px = xyz + (size_t)b * Nn * 3;
    const float qx = newxyz[bs * 3 + 0];
    const float qy = newxyz[bs * 3 + 1];
    const float qz = newxyz[bs * 3 + 2];
    const float qq = (qx * qx + qy * qy) + qz * qz;
    unsigned long long mkey = ~0ull;
#pragma unroll 4
    for (int u = 0; u < 64; ++u) {
        const int n = t + (u << 8);
        const float bx = px[n * 3 + 0];
        const float by = px[n * 3 + 1];
        const float bz = px[n * 3 + 2];
        const float bb2 = (bx * bx + by * by) + bz * bz;
        const float ab = (qx * bx + qy * by) + qz * bz;
        const float d = (qq + bb2) - 2.0f * ab;   // exact reference formula
        unsigned u32 = __float_as_uint(d);
        u32 = ((int)u32 < 0) ? ~u32 : (u32 | 0x80000000u);  // sortable transform
        s_key[n] = u32;
        const unsigned long long k = ((unsigned long long)u32 << 32) | (unsigned)n;
        mkey = (k < mkey) ? k : mkey;
    }
    __syncthreads();
    for (int r = 0; r < KNEI; ++r) {
        unsigned long long k = mkey;
#pragma unroll
        for (int off = 32; off > 0; off >>= 1) {
            const unsigned long long o = __shfl_xor(k, off);
            k = (o < k) ? o : k;
        }
        if ((t & 63) == 0) s_wred[t >> 6] = k;
        __syncthreads();
        if (t == 0) {
            unsigned long long w = s_wred[0];
            if (s_wred[1] < w) w = s_wred[1];
            if (s_wred[2] < w) w = s_wred[2];
            if (s_wred[3] < w) w = s_wred[3];
            s_win = w;
            s_nidx[r] = (int)(unsigned)(w & 0xFFFFFFFFull);
        }
        __syncthreads();
        const unsigned long long w = s_win;
        if (w == mkey) {  // unique owner: invalidate + rescan own 64 slots
            const int wn = (int)(unsigned)(w & 0xFFFFFFFFull);
            s_key[wn] = 0xFFFFFFFFu;
            mkey = ~0ull;
#pragma unroll 4
            for (int u = 0; u < 64; ++u) {
                const int n = t + (u << 8);
                const unsigned long long kk =
                    ((unsigned long long)s_key[n] << 32) | (unsigned)n;
                mkey = (kk < mkey) ? kk : mkey;
            }
        }
        __syncthreads();
    }
    // gather + maxpool + add points_ori (already in pre)
    const float po = pre[(size_t)bs * DIMn + t];
    float m = -__builtin_huge_valf();
#pragma unroll
    for (int r = 0; r < KNEI; ++r) {
        const int n = s_nidx[r];
        m = fmaxf(m, h[((size_t)b * Nn + n) * DIMn + t]);
    }
    pre[(size_t)bs * DIMn + t] = po + m;
}

// ---------------------------------------------------------------------------
// final BN apply: out = pre*sc + sh
// ---------------------------------------------------------------------------
__global__ __launch_bounds__(256) void apply_bn_kernel(const float* __restrict__ pre,
                                                       const float* __restrict__ sc,
                                                       const float* __restrict__ sh,
                                                       float* __restrict__ out)
{
    const size_t i = (size_t)blockIdx.x * 256 + threadIdx.x;
    const int c4 = (int)(i & 63);
    const float4 v = reinterpret_cast<const float4*>(pre)[i];
    const float4 s4 = reinterpret_cast<const float4*>(sc)[c4];
    const float4 b4 = reinterpret_cast<const float4*>(sh)[c4];
    float4 o;
    o.x = fmaf(v.x, s4.x, b4.x);
    o.y = fmaf(v.y, s4.y, b4.y);
    o.z = fmaf(v.z, s4.z, b4.z);
    o.w = fmaf(v.w, s4.w, b4.w);
    reinterpret_cast<float4*>(out)[i] = o;
}

// ---------------------------------------------------------------------------
// Launch. Workspace layout (bytes), requires ws_size >= ~211 MB:
//   [0,64Mi)      h0  (fc1 out, then final h after residual)
//   [64Mi,128Mi)  A1  (conv1 pre-BN)
//   [128Mi,192Mi) A2  (conv2 pre-BN)
//   [192Mi,200Mi) pre (points_ori, then new_points pre-BN)  8 MB
//   [200Mi,+32K)  fps_idx
//   [201Mi, ...)  ps/pq partials (512 KB) + 6x256 scale/shift
// ---------------------------------------------------------------------------
extern "C" void kernel_launch(void* const* d_in, const int* in_sizes, int n_in,
                              void* d_out, int out_size, void* d_ws, size_t ws_size,
                              hipStream_t stream)
{
    (void)in_sizes; (void)n_in; (void)out_size; (void)ws_size;
    const float* xyz     = (const float*)d_in[0];
    const float* points  = (const float*)d_in[1];
    const float* fc1_w   = (const float*)d_in[2];
    const float* fc1_b   = (const float*)d_in[3];
    const float* conv1_w = (const float*)d_in[4];
    const float* conv1_b = (const float*)d_in[5];
    const float* conv2_w = (const float*)d_in[6];
    const float* conv2_b = (const float*)d_in[7];
    const float* bn1_g   = (const float*)d_in[8];
    const float* bn1_b   = (const float*)d_in[9];
    const float* bn2_g   = (const float*)d_in[10];
    const float* bn2_b   = (const float*)d_in[11];
    const float* bn_g    = (const float*)d_in[12];
    const float* bn_b    = (const float*)d_in[13];

    float* out = (float*)d_out;
    float* newxyz = out;                       // [4,2048,3]
    float* outpts = out + (size_t)Bn * Sn * 3; // [4,2048,256]

    char* w = (char*)d_ws;
    float* h0   = (float*)(w);
    float* A1   = (float*)(w + (64ull << 20));
    float* A2   = (float*)(w + (128ull << 20));
    float* pre  = (float*)(w + (192ull << 20));
    int*   fidx = (int*)  (w + (200ull << 20));
    float* ps   = (float*)(w + (201ull << 20));
    float* pq   = ps + 256 * 256;
    float* sc1  = pq + 256 * 256;
    float* sh1  = sc1 + 256;
    float* sc2  = sh1 + 256;
    float* sh2  = sc2 + 256;
    float* sc3  = sh2 + 256;
    float* sh3  = sc3 + 256;

    // 1. FPS (writes fps_idx + new_xyz directly into d_out)
    fps_kernel<<<Bn, 512, 0, stream>>>(xyz, fidx, newxyz);
    // 2. h0 = points @ fc1_w + fc1_b
    gemm_k<false, false><<<dim3(MROWS / 64, DIMn / 64), 256, 0, stream>>>(
        points, fc1_w, fc1_b, nullptr, nullptr, h0, CINn);
    // 3. points_ori = h0[fps_idx]  (gathered BEFORE h0 is updated)
    gather_po_kernel<<<SROWS, 256, 0, stream>>>(h0, fidx, pre);
    // 4. A1 = h0 @ conv1_w.T + conv1_b ; BN1 stats
    gemm_k<true, false><<<dim3(MROWS / 64, DIMn / 64), 256, 0, stream>>>(
        h0, conv1_w, conv1_b, nullptr, nullptr, A1, DIMn);
    stats_partial<<<256, 256, 0, stream>>>(A1, MROWS / 256, ps, pq);
    bn_finalize<<<1, 256, 0, stream>>>(ps, pq, 256, 1.0f / MROWS, bn1_g, bn1_b, sc1, sh1);
    // 5. A2 = relu(BN1(A1)) @ conv2_w.T + conv2_b ; BN2 stats
    gemm_k<true, true><<<dim3(MROWS / 64, DIMn / 64), 256, 0, stream>>>(
        A1, conv2_w, conv2_b, sc1, sh1, A2, DIMn);
    stats_partial<<<256, 256, 0, stream>>>(A2, MROWS / 256, ps, pq);
    bn_finalize<<<1, 256, 0, stream>>>(ps, pq, 256, 1.0f / MROWS, bn2_g, bn2_b, sc2, sh2);
    // 6. h0 += relu(BN2(A2))   (h0 becomes final h)
    residual_kernel<<<(MROWS * DIMn / 4) / 256, 256, 0, stream>>>(h0, A2, sc2, sh2);
    // 7. 16-NN + gather + maxpool: pre = points_ori + max_k h[idx_k]
    topk_group<<<SROWS, 256, 0, stream>>>(xyz, newxyz, h0, pre);
    // 8. final BN over [B*S, D]
    stats_partial<<<64, 256, 0, stream>>>(pre, SROWS / 64, ps, pq);
    bn_finalize<<<1, 256, 0, stream>>>(ps, pq, 64, 1.0f / SROWS, bn_g, bn_b, sc3, sh3);
    apply_bn_kernel<<<(SROWS * DIMn / 4) / 256, 256, 0, stream>>>(pre, sc3, sh3, outpts);
}